// Round 1
// 497.809 us; speedup vs baseline: 1.2085x; 1.2085x over previous
//
#include <hip/hip_runtime.h>
#include <hip/hip_bf16.h>

// Problem constants
#define NNODES 100000
#define NEDGES 300000
#define FIN 128
#define HDIM 256
#define NLAYERS 3
#define MPAD 100096  // 782 * 128 — all GEMMs compute exactly MPAD rows, no predicates

typedef float f32x4 __attribute__((ext_vector_type(4)));
typedef short bf16x8 __attribute__((ext_vector_type(8)));

__device__ inline float bf2f(unsigned short u) {
    union { unsigned int i; float f; } v;
    v.i = ((unsigned int)u) << 16;
    return v.f;
}
__device__ inline unsigned short f2bf(float f) {  // RNE
    union { float f; unsigned int i; } v;
    v.f = f;
    return (unsigned short)((v.i + 0x7fffu + ((v.i >> 16) & 1u)) >> 16);
}

// 16-byte async global->LDS (dest = wave-uniform base + lane*16)
__device__ __forceinline__ void gll16(const unsigned short* g, unsigned short* l) {
    __builtin_amdgcn_global_load_lds(
        (const __attribute__((address_space(1))) unsigned int*)g,
        (__attribute__((address_space(3))) unsigned int*)l, 16, 0, 0);
}

// ---------------------------------------------------------------------------
// 2-phase LDS-staged MFMA GEMM (m97-style structure).
// C[M,256] tile: 128 rows x 128 cols per block, 4 waves (wave = 64x64 via
// 4x4 of 16x16x32 MFMA), BK=32, double-buffered LDS (32 KiB).
// Staging uses global_load_lds width=16 with LINEAR LDS dest; bank conflicts
// on ds_read_b128 are avoided by pre-swizzling the global SOURCE address and
// applying the same XOR on the read side (slot ^= (row>>1)&3) — 2-way max.
// A: bf16 [.][K] row-major.  Bt: bf16 [256][K] (pre-transposed).  C: bf16.
// M must be a multiple of 128 (grid.y = M/128); N tile via grid.x in {0,1}.
// ---------------------------------------------------------------------------
template <int K, bool BIAS, bool RELU>
__global__ __launch_bounds__(256) void gemm_lds_k(
    const unsigned short* __restrict__ A, const unsigned short* __restrict__ Bt,
    const float* __restrict__ bias, unsigned short* __restrict__ C) {
    constexpr int BK = 32;        // 64 B per LDS row
    constexpr int NT = K / BK;
    __shared__ unsigned short sA[2][128 * BK];
    __shared__ unsigned short sB[2][128 * BK];

    const int tid  = threadIdx.x;
    const int lane = tid & 63;
    const int wid  = tid >> 6;
    const int r15  = lane & 15;
    const int kq   = lane >> 4;        // 0..3
    const int wr   = wid >> 1;         // wave row-tile (0/1)
    const int wc   = wid & 1;          // wave col-tile (0/1)
    const int rowblk = blockIdx.y * 128;
    const int colblk = blockIdx.x * 128;

    // Staging geometry: wave w, chunk q covers LDS rows [q*64 + w*16, +16),
    // each row = 64 B; lane L writes row (L>>2), phys slot (L&3).
    // Phys slot p at row r holds logical k-slot p ^ ((r>>1)&3)  (involution).
    const unsigned short* gA[2];
    const unsigned short* gB[2];
    int ldsbase[2];
#pragma unroll
    for (int q = 0; q < 2; ++q) {
        int rr   = q * 64 + wid * 16 + (lane >> 2);
        int slot = (lane & 3) ^ ((rr >> 1) & 3);
        gA[q] = A  + (size_t)(rowblk + rr) * K + slot * 8;
        gB[q] = Bt + (size_t)(colblk + rr) * K + slot * 8;
        ldsbase[q] = (q * 64 + wid * 16) * BK;   // wave-uniform
    }

    // Read-side swizzled fragment offsets (elements)
    const int sread = ((kq ^ ((r15 >> 1) & 3)) * 8);
    int aoff[4], boff[4];
#pragma unroll
    for (int i = 0; i < 4; ++i) {
        aoff[i] = (wr * 64 + i * 16 + r15) * BK + sread;
        boff[i] = (wc * 64 + i * 16 + r15) * BK + sread;
    }

    f32x4 acc[4][4] = {};

    // prologue: stage K-tile 0 into buf 0
#pragma unroll
    for (int q = 0; q < 2; ++q) {
        gll16(gA[q], &sA[0][ldsbase[q]]);
        gll16(gB[q], &sB[0][ldsbase[q]]);
    }
    __syncthreads();  // vmcnt(0) drain included by compiler

#pragma unroll
    for (int t = 0; t < NT; ++t) {
        // issue next K-tile's staging before compute (overlaps with MFMA)
        if (t + 1 < NT) {
#pragma unroll
            for (int q = 0; q < 2; ++q) {
                gll16(gA[q] + (t + 1) * BK, &sA[(t + 1) & 1][ldsbase[q]]);
                gll16(gB[q] + (t + 1) * BK, &sB[(t + 1) & 1][ldsbase[q]]);
            }
        }
        bf16x8 a[4], b[4];
#pragma unroll
        for (int i = 0; i < 4; ++i) a[i] = *(const bf16x8*)&sA[t & 1][aoff[i]];
#pragma unroll
        for (int j = 0; j < 4; ++j) b[j] = *(const bf16x8*)&sB[t & 1][boff[j]];
#pragma unroll
        for (int i = 0; i < 4; ++i)
#pragma unroll
            for (int j = 0; j < 4; ++j)
                acc[i][j] = __builtin_amdgcn_mfma_f32_16x16x32_bf16(a[i], b[j], acc[i][j], 0, 0, 0);
        __syncthreads();  // one barrier per K-step: drains this step's staging
    }

    // Epilogue: C/D layout col = lane&15, row = (lane>>4)*4 + reg
#pragma unroll
    for (int i = 0; i < 4; ++i) {
#pragma unroll
        for (int reg = 0; reg < 4; ++reg) {
            int row = rowblk + wr * 64 + i * 16 + kq * 4 + reg;
#pragma unroll
            for (int j = 0; j < 4; ++j) {
                int col = colblk + wc * 64 + j * 16 + r15;
                float v = acc[i][j][reg];
                if (BIAS) v += bias[col];
                if (RELU) v = fmaxf(v, 0.0f);
                C[(size_t)row * HDIM + col] = f2bf(v);
            }
        }
    }
}

// ---------------------------------------------------------------------------
// Weight prep: W[nm][K][256] fp32 -> Wt[nm][256][K] bf16 (transpose+convert)
// ---------------------------------------------------------------------------
__global__ void wprep_k(const float* __restrict__ W, unsigned short* __restrict__ Wt,
                        int K, int total) {
    int i = blockIdx.x * blockDim.x + threadIdx.x;
    if (i >= total) return;
    int mat = i / (K * 256);
    int r = i - mat * (K * 256);
    int k = r >> 8, p = r & 255;
    Wt[(size_t)mat * K * 256 + (size_t)p * K + k] = f2bf(W[i]);
}

// Straight fp32 -> bf16 convert (no transpose), vectorized x4
__global__ void conv_k(const float* __restrict__ W, unsigned short* __restrict__ o, int n4) {
    int i = blockIdx.x * blockDim.x + threadIdx.x;
    if (i >= n4) return;
    float4 v = ((const float4*)W)[i];
    ushort4 u;
    u.x = f2bf(v.x); u.y = f2bf(v.y); u.z = f2bf(v.z); u.w = f2bf(v.w);
    ((ushort4*)o)[i] = u;
}

// foldb[c] = sum_j b2[j] * G0[j][c]   (G0 = gcn_w layer 0, row-major fp32)
__global__ void foldbias_k(const float* __restrict__ b2, const float* __restrict__ g0,
                           float* __restrict__ fb) {
    int c = threadIdx.x;  // one block of 256
    float s = 0.0f;
#pragma unroll 8
    for (int j = 0; j < HDIM; ++j) s += b2[j] * g0[(size_t)j * HDIM + c];
    fb[c] = s;
}

// ---------------------------------------------------------------------------
// CSR build utilities
// ---------------------------------------------------------------------------
__global__ void zero_k(unsigned* __restrict__ p, int n) {
    int i = blockIdx.x * blockDim.x + threadIdx.x;
    if (i < n) p[i] = 0u;
}

__global__ void count_k(const int* __restrict__ dst, unsigned* __restrict__ cnt, int E) {
    int e = blockIdx.x * blockDim.x + threadIdx.x;
    if (e < E) atomicAdd(&cnt[dst[e]], 1u);
}

// scan1 also computes dinv and zeroes cnt (cursor reuse) — saves 2 launches
__global__ __launch_bounds__(256) void scan1_k(unsigned* __restrict__ cnt,
                                               int* __restrict__ rs,
                                               unsigned* __restrict__ blocksum,
                                               float* __restrict__ dinv, int N) {
    __shared__ unsigned tmp[256];
    int tid = threadIdx.x;
    int gid = blockIdx.x * 256 + tid;
    unsigned v = (gid < N) ? cnt[gid] : 0u;
    if (gid < N) {
        dinv[gid] = 1.0f / sqrtf((float)(v + 1u));  // +1 = self loop
        cnt[gid] = 0u;                               // reset for cursor use
    }
    tmp[tid] = v;
    __syncthreads();
#pragma unroll
    for (int off = 1; off < 256; off <<= 1) {
        unsigned t = (tid >= off) ? tmp[tid - off] : 0u;
        __syncthreads();
        tmp[tid] += t;
        __syncthreads();
    }
    if (gid < N) rs[gid] = (int)(tmp[tid] - v);
    if (tid == 255) blocksum[blockIdx.x] = tmp[tid];
}

__global__ __launch_bounds__(512) void scan2_k(unsigned* __restrict__ blocksum, int nb) {
    __shared__ unsigned tmp[512];
    int tid = threadIdx.x;
    unsigned v = (tid < nb) ? blocksum[tid] : 0u;
    tmp[tid] = v;
    __syncthreads();
#pragma unroll
    for (int off = 1; off < 512; off <<= 1) {
        unsigned t = (tid >= off) ? tmp[tid - off] : 0u;
        __syncthreads();
        tmp[tid] += t;
        __syncthreads();
    }
    if (tid < nb) blocksum[tid] = tmp[tid] - v;
}

__global__ void scan3_k(int* __restrict__ rs, const unsigned* __restrict__ blocksum, int N, int E) {
    int gid = blockIdx.x * blockDim.x + threadIdx.x;
    if (gid < N) rs[gid] += (int)blocksum[gid >> 8];
    if (gid == 0) rs[N] = E;
}

__global__ void fill_k(const int* __restrict__ src, const int* __restrict__ dst,
                       const int* __restrict__ rs, unsigned* __restrict__ cursor,
                       const float* __restrict__ dinv,
                       int* __restrict__ srcs, float* __restrict__ ww, int E) {
    int e = blockIdx.x * blockDim.x + threadIdx.x;
    if (e >= E) return;
    int s = src[e], d = dst[e];
    int pos = rs[d] + (int)atomicAdd(&cursor[d], 1u);
    srcs[pos] = s;
    ww[pos] = dinv[s] * dinv[d];
}

// ---------------------------------------------------------------------------
// CSR gather-aggregate (bf16 m), fused self-loop + bias + ReLU.
// One wave per node; ushort4 (4 cols) per lane.
// ---------------------------------------------------------------------------
template <bool OUTF32>
__global__ __launch_bounds__(256) void gather_k(const int* __restrict__ rs,
                                                const int* __restrict__ srcs,
                                                const float* __restrict__ ww,
                                                const float* __restrict__ dinv,
                                                const unsigned short* __restrict__ m,
                                                const float* __restrict__ bias,
                                                void* __restrict__ out, int N) {
    int node = blockIdx.x * 4 + (threadIdx.x >> 6);
    int lane = threadIdx.x & 63;
    if (node >= N) return;
    int beg = rs[node], end = rs[node + 1];
    float d = dinv[node];
    float w0 = d * d;
    ushort4 u = ((const ushort4*)(m + (size_t)node * HDIM))[lane];
    float ax = bf2f(u.x) * w0, ay = bf2f(u.y) * w0, az = bf2f(u.z) * w0, aw = bf2f(u.w) * w0;
    for (int e = beg; e < end; ++e) {
        int s = srcs[e];
        float w = ww[e];
        ushort4 v = ((const ushort4*)(m + (size_t)s * HDIM))[lane];
        ax += bf2f(v.x) * w;
        ay += bf2f(v.y) * w;
        az += bf2f(v.z) * w;
        aw += bf2f(v.w) * w;
    }
    float4 b = ((const float4*)bias)[lane];
    ax = fmaxf(ax + b.x, 0.0f);
    ay = fmaxf(ay + b.y, 0.0f);
    az = fmaxf(az + b.z, 0.0f);
    aw = fmaxf(aw + b.w, 0.0f);
    if (OUTF32) {
        float4 o = {ax, ay, az, aw};
        ((float4*)out)[(size_t)node * 64 + lane] = o;
    } else {
        ushort4 o;
        o.x = f2bf(ax); o.y = f2bf(ay); o.z = f2bf(az); o.w = f2bf(aw);
        ((ushort4*)out)[(size_t)node * 64 + lane] = o;
    }
}

extern "C" void kernel_launch(void* const* d_in, const int* in_sizes, int n_in,
                              void* d_out, int out_size, void* d_ws, size_t ws_size,
                              hipStream_t stream) {
    const float* x  = (const float*)d_in[0];
    const int* ei   = (const int*)d_in[1];
    const float* w1 = (const float*)d_in[2];
    const float* b1 = (const float*)d_in[3];
    const float* w2 = (const float*)d_in[4];
    const float* b2 = (const float*)d_in[5];
    const float* gw = (const float*)d_in[6];
    const float* gb = (const float*)d_in[7];

    const int N = NNODES, E = NEDGES;
    const int* src = ei;
    const int* dst = ei + E;

    // Workspace layout (~158 MB)
    char* p = (char*)d_ws;
    unsigned short* h1   = (unsigned short*)p; p += (size_t)MPAD * HDIM * 2;  // 51.2 MB
    unsigned short* h    = (unsigned short*)p; p += (size_t)MPAD * HDIM * 2;
    unsigned short* m    = (unsigned short*)p; p += (size_t)MPAD * HDIM * 2;
    unsigned short* w1t  = (unsigned short*)p; p += (size_t)FIN * HDIM * 2;
    unsigned short* gwt  = (unsigned short*)p; p += (size_t)NLAYERS * HDIM * HDIM * 2;
    unsigned short* w2c  = (unsigned short*)p; p += (size_t)HDIM * HDIM * 2;   // w2 bf16 row-major
    unsigned short* fBt  = (unsigned short*)p; p += (size_t)HDIM * HDIM * 2;   // folded W2*G0, Bt layout
    float* foldb = (float*)p;          p += (size_t)HDIM * 4;                  // folded bias b2*G0
    unsigned* cnt = (unsigned*)p;      p += (size_t)N * 4;
    float* dinv = (float*)p;           p += (size_t)N * 4;
    int* rs = (int*)p;                 p += (size_t)(N + 1) * 4 + 12;
    unsigned* blocksum = (unsigned*)p; p += 512 * 4;
    int* srcs = (int*)p;               p += (size_t)E * 4;
    float* wwt = (float*)p;            p += (size_t)E * 4;

    // xb: x converted to bf16 [MPAD][FIN] — reuses the idle m buffer (25.6 MB < 51.2 MB)
    unsigned short* xb = m;

    const int nb = (N + 255) / 256;             // 391
    const dim3 ggrid(2, MPAD / 128);            // 1564 blocks, 128x128 tiles

    // ---- Weight conversion + x -> bf16 ----
    wprep_k<<<(FIN * 256 + 255) / 256, 256, 0, stream>>>(w1, w1t, FIN, FIN * 256);
    wprep_k<<<(NLAYERS * HDIM * 256 + 255) / 256, 256, 0, stream>>>(gw, gwt, HDIM, NLAYERS * HDIM * 256);
    conv_k<<<(HDIM * HDIM / 4 + 255) / 256, 256, 0, stream>>>(w2, w2c, HDIM * HDIM / 4);
    conv_k<<<(N * FIN / 4 + 255) / 256, 256, 0, stream>>>(x, xb, N * FIN / 4);

    // ---- Fold: fBt[c][k'] = sum_j G0[j][c]*W2[k'][j];  foldb[c] = sum_j b2[j]*G0[j][c]
    foldbias_k<<<1, 256, 0, stream>>>(b2, gw, foldb);
    gemm_lds_k<HDIM, false, false><<<dim3(2, 2), 256, 0, stream>>>(gwt, w2c, nullptr, fBt);

    // ---- CSR build (6 launches) ----
    zero_k<<<nb, 256, 0, stream>>>(cnt, N);
    count_k<<<(E + 255) / 256, 256, 0, stream>>>(dst, cnt, E);
    scan1_k<<<nb, 256, 0, stream>>>(cnt, rs, blocksum, dinv, N);
    scan2_k<<<1, 512, 0, stream>>>(blocksum, nb);
    scan3_k<<<nb + 1, 256, 0, stream>>>(rs, blocksum, N, E);
    fill_k<<<(E + 255) / 256, 256, 0, stream>>>(src, dst, rs, cnt, dinv, srcs, wwt, E);

    // ---- Encoder GEMM1: h1 = relu(xb @ W1 + b1) ----
    gemm_lds_k<FIN, true, true><<<ggrid, 256, 0, stream>>>(xb, w1t, b1, h1);

    // ---- Layer 0 (folded): m = h1 @ (W2*G0) + b2*G0  (overwrites xb — already consumed)
    gemm_lds_k<HDIM, true, false><<<ggrid, 256, 0, stream>>>(h1, fBt, foldb, m);
    gather_k<false><<<(N + 3) / 4, 256, 0, stream>>>(rs, srcs, wwt, dinv, m, gb, h, N);

    // ---- Layers 1..2 ----
    for (int l = 1; l < NLAYERS; ++l) {
        const unsigned short* wl = gwt + (size_t)l * HDIM * HDIM;
        const float* bl = gb + (size_t)l * HDIM;
        gemm_lds_k<HDIM, false, false><<<ggrid, 256, 0, stream>>>(h, wl, nullptr, m);
        if (l < NLAYERS - 1)
            gather_k<false><<<(N + 3) / 4, 256, 0, stream>>>(rs, srcs, wwt, dinv, m, bl, h, N);
        else
            gather_k<true><<<(N + 3) / 4, 256, 0, stream>>>(rs, srcs, wwt, dinv, m, bl, d_out, N);
    }
}

// Round 2
// 463.696 us; speedup vs baseline: 1.2975x; 1.0736x over previous
//
#include <hip/hip_runtime.h>
#include <hip/hip_bf16.h>

// Problem constants
#define NNODES 100000
#define NEDGES 300000
#define FIN 128
#define HDIM 256
#define NLAYERS 3
#define MPAD 100096  // 782 * 128 — all GEMMs compute exactly MPAD rows, no predicates

typedef float f32x4 __attribute__((ext_vector_type(4)));
typedef short bf16x8 __attribute__((ext_vector_type(8)));

__device__ inline float bf2f(unsigned short u) {
    union { unsigned int i; float f; } v;
    v.i = ((unsigned int)u) << 16;
    return v.f;
}
__device__ inline unsigned short f2bf(float f) {  // RNE
    union { float f; unsigned int i; } v;
    v.f = f;
    return (unsigned short)((v.i + 0x7fffu + ((v.i >> 16) & 1u)) >> 16);
}

// 16-byte async global->LDS (dest = wave-uniform base + lane*16)
__device__ __forceinline__ void gll16(const unsigned short* g, unsigned short* l) {
    __builtin_amdgcn_global_load_lds(
        (const __attribute__((address_space(1))) unsigned int*)g,
        (__attribute__((address_space(3))) unsigned int*)l, 16, 0, 0);
}

// ---------------------------------------------------------------------------
// 2-phase LDS-staged MFMA GEMM (m97-style structure).
// C[M,256] tile: 128 rows x 128 cols per block, 4 waves (wave = 64x64 via
// 4x4 of 16x16x32 MFMA), BK=32, double-buffered LDS (32 KiB).
// Staging uses global_load_lds width=16 with LINEAR LDS dest; bank conflicts
// on ds_read_b128 are avoided by pre-swizzling the global SOURCE address and
// applying the same XOR on the read side (slot ^= (row>>1)&3) — 2-way max.
// A: bf16 [.][K] row-major.  Bt: bf16 [256][K] (pre-transposed).  C: bf16.
// M must be a multiple of 128 (grid.y = M/128); N tile via grid.x in {0,1}.
// ---------------------------------------------------------------------------
template <int K, bool BIAS, bool RELU>
__global__ __launch_bounds__(256) void gemm_lds_k(
    const unsigned short* __restrict__ A, const unsigned short* __restrict__ Bt,
    const float* __restrict__ bias, unsigned short* __restrict__ C) {
    constexpr int BK = 32;        // 64 B per LDS row
    constexpr int NT = K / BK;
    __shared__ unsigned short sA[2][128 * BK];
    __shared__ unsigned short sB[2][128 * BK];

    const int tid  = threadIdx.x;
    const int lane = tid & 63;
    const int wid  = tid >> 6;
    const int r15  = lane & 15;
    const int kq   = lane >> 4;        // 0..3
    const int wr   = wid >> 1;         // wave row-tile (0/1)
    const int wc   = wid & 1;          // wave col-tile (0/1)
    const int rowblk = blockIdx.y * 128;
    const int colblk = blockIdx.x * 128;

    // Staging geometry: wave w, chunk q covers LDS rows [q*64 + w*16, +16),
    // each row = 64 B; lane L writes row (L>>2), phys slot (L&3).
    // Phys slot p at row r holds logical k-slot p ^ ((r>>1)&3)  (involution).
    const unsigned short* gA[2];
    const unsigned short* gB[2];
    int ldsbase[2];
#pragma unroll
    for (int q = 0; q < 2; ++q) {
        int rr   = q * 64 + wid * 16 + (lane >> 2);
        int slot = (lane & 3) ^ ((rr >> 1) & 3);
        gA[q] = A  + (size_t)(rowblk + rr) * K + slot * 8;
        gB[q] = Bt + (size_t)(colblk + rr) * K + slot * 8;
        ldsbase[q] = (q * 64 + wid * 16) * BK;   // wave-uniform
    }

    // Read-side swizzled fragment offsets (elements)
    const int sread = ((kq ^ ((r15 >> 1) & 3)) * 8);
    int aoff[4], boff[4];
#pragma unroll
    for (int i = 0; i < 4; ++i) {
        aoff[i] = (wr * 64 + i * 16 + r15) * BK + sread;
        boff[i] = (wc * 64 + i * 16 + r15) * BK + sread;
    }

    f32x4 acc[4][4] = {};

    // prologue: stage K-tile 0 into buf 0
#pragma unroll
    for (int q = 0; q < 2; ++q) {
        gll16(gA[q], &sA[0][ldsbase[q]]);
        gll16(gB[q], &sB[0][ldsbase[q]]);
    }
    __syncthreads();  // vmcnt(0) drain included by compiler

#pragma unroll
    for (int t = 0; t < NT; ++t) {
        // issue next K-tile's staging before compute (overlaps with MFMA)
        if (t + 1 < NT) {
#pragma unroll
            for (int q = 0; q < 2; ++q) {
                gll16(gA[q] + (t + 1) * BK, &sA[(t + 1) & 1][ldsbase[q]]);
                gll16(gB[q] + (t + 1) * BK, &sB[(t + 1) & 1][ldsbase[q]]);
            }
        }
        bf16x8 a[4], b[4];
#pragma unroll
        for (int i = 0; i < 4; ++i) a[i] = *(const bf16x8*)&sA[t & 1][aoff[i]];
#pragma unroll
        for (int j = 0; j < 4; ++j) b[j] = *(const bf16x8*)&sB[t & 1][boff[j]];
#pragma unroll
        for (int i = 0; i < 4; ++i)
#pragma unroll
            for (int j = 0; j < 4; ++j)
                acc[i][j] = __builtin_amdgcn_mfma_f32_16x16x32_bf16(a[i], b[j], acc[i][j], 0, 0, 0);
        __syncthreads();  // one barrier per K-step: drains this step's staging
    }

    // Epilogue: C/D layout col = lane&15, row = (lane>>4)*4 + reg
#pragma unroll
    for (int i = 0; i < 4; ++i) {
#pragma unroll
        for (int reg = 0; reg < 4; ++reg) {
            int row = rowblk + wr * 64 + i * 16 + kq * 4 + reg;
#pragma unroll
            for (int j = 0; j < 4; ++j) {
                int col = colblk + wc * 64 + j * 16 + r15;
                float v = acc[i][j][reg];
                if (BIAS) v += bias[col];
                if (RELU) v = fmaxf(v, 0.0f);
                C[(size_t)row * HDIM + col] = f2bf(v);
            }
        }
    }
}

// ---------------------------------------------------------------------------
// Weight prep: W[nm][K][256] fp32 -> Wt[nm][256][K] bf16 (transpose+convert)
// ---------------------------------------------------------------------------
__global__ void wprep_k(const float* __restrict__ W, unsigned short* __restrict__ Wt,
                        int K, int total) {
    int i = blockIdx.x * blockDim.x + threadIdx.x;
    if (i >= total) return;
    int mat = i / (K * 256);
    int r = i - mat * (K * 256);
    int k = r >> 8, p = r & 255;
    Wt[(size_t)mat * K * 256 + (size_t)p * K + k] = f2bf(W[i]);
}

// Straight fp32 -> bf16 convert (no transpose), vectorized x4
__global__ void conv_k(const float* __restrict__ W, unsigned short* __restrict__ o, int n4) {
    int i = blockIdx.x * blockDim.x + threadIdx.x;
    if (i >= n4) return;
    float4 v = ((const float4*)W)[i];
    ushort4 u;
    u.x = f2bf(v.x); u.y = f2bf(v.y); u.z = f2bf(v.z); u.w = f2bf(v.w);
    ((ushort4*)o)[i] = u;
}

// foldb[c] = sum_j b2[j] * G0[j][c]   (G0 = gcn_w layer 0, row-major fp32)
__global__ void foldbias_k(const float* __restrict__ b2, const float* __restrict__ g0,
                           float* __restrict__ fb) {
    int c = threadIdx.x;  // one block of 256
    float s = 0.0f;
#pragma unroll 8
    for (int j = 0; j < HDIM; ++j) s += b2[j] * g0[(size_t)j * HDIM + c];
    fb[c] = s;
}

// ---------------------------------------------------------------------------
// CSR build utilities
// ---------------------------------------------------------------------------
__global__ void zero_k(unsigned* __restrict__ p, int n) {
    int i = blockIdx.x * blockDim.x + threadIdx.x;
    if (i < n) p[i] = 0u;
}

__global__ void count_k(const int* __restrict__ dst, unsigned* __restrict__ cnt, int E) {
    int e = blockIdx.x * blockDim.x + threadIdx.x;
    if (e < E) atomicAdd(&cnt[dst[e]], 1u);
}

// scan1 also computes dinv and zeroes cnt (cursor reuse) — saves 2 launches
__global__ __launch_bounds__(256) void scan1_k(unsigned* __restrict__ cnt,
                                               int* __restrict__ rs,
                                               unsigned* __restrict__ blocksum,
                                               float* __restrict__ dinv, int N) {
    __shared__ unsigned tmp[256];
    int tid = threadIdx.x;
    int gid = blockIdx.x * 256 + tid;
    unsigned v = (gid < N) ? cnt[gid] : 0u;
    if (gid < N) {
        dinv[gid] = 1.0f / sqrtf((float)(v + 1u));  // +1 = self loop
        cnt[gid] = 0u;                               // reset for cursor use
    }
    tmp[tid] = v;
    __syncthreads();
#pragma unroll
    for (int off = 1; off < 256; off <<= 1) {
        unsigned t = (tid >= off) ? tmp[tid - off] : 0u;
        __syncthreads();
        tmp[tid] += t;
        __syncthreads();
    }
    if (gid < N) rs[gid] = (int)(tmp[tid] - v);
    if (tid == 255) blocksum[blockIdx.x] = tmp[tid];
}

__global__ __launch_bounds__(512) void scan2_k(unsigned* __restrict__ blocksum, int nb) {
    __shared__ unsigned tmp[512];
    int tid = threadIdx.x;
    unsigned v = (tid < nb) ? blocksum[tid] : 0u;
    tmp[tid] = v;
    __syncthreads();
#pragma unroll
    for (int off = 1; off < 512; off <<= 1) {
        unsigned t = (tid >= off) ? tmp[tid - off] : 0u;
        __syncthreads();
        tmp[tid] += t;
        __syncthreads();
    }
    if (tid < nb) blocksum[tid] = tmp[tid] - v;
}

__global__ void scan3_k(int* __restrict__ rs, const unsigned* __restrict__ blocksum, int N, int E) {
    int gid = blockIdx.x * blockDim.x + threadIdx.x;
    if (gid < N) rs[gid] += (int)blocksum[gid >> 8];
    if (gid == 0) rs[N] = E;
}

// fill_k now packs (src, weight) into one int2 per edge — single 8B load in gather
__global__ void fill_k(const int* __restrict__ src, const int* __restrict__ dst,
                       const int* __restrict__ rs, unsigned* __restrict__ cursor,
                       const float* __restrict__ dinv,
                       int2* __restrict__ edata, int E) {
    int e = blockIdx.x * blockDim.x + threadIdx.x;
    if (e >= E) return;
    int s = src[e], d = dst[e];
    int pos = rs[d] + (int)atomicAdd(&cursor[d], 1u);
    float w = dinv[s] * dinv[d];
    edata[pos] = make_int2(s, __float_as_int(w));
}

// ---------------------------------------------------------------------------
// CSR gather-aggregate (bf16 m), fused self-loop + bias + ReLU.
// One wave per node; ushort4 (4 cols) per lane.
// Latency fix: cooperative edge-metadata load (edata[beg+lane], one coalesced
// 8B/lane shot) + register shuffle broadcast + 4-wide unrolled independent
// row gathers. Masked slots carry (s=0, w=0.0): weight-0 read of row 0 (L1-
// hot) contributes exactly 0, so no remainder loop — dependent chain per node
// drops from deg*(meta_lat + row_lat) to ~1 row_lat for deg<=4.
// ---------------------------------------------------------------------------
template <bool OUTF32>
__global__ __launch_bounds__(256) void gather_k(const int* __restrict__ rs,
                                                const int2* __restrict__ edata,
                                                const float* __restrict__ dinv,
                                                const unsigned short* __restrict__ m,
                                                const float* __restrict__ bias,
                                                void* __restrict__ out, int N) {
    int node = blockIdx.x * 4 + (threadIdx.x >> 6);
    int lane = threadIdx.x & 63;
    if (node >= N) return;
    int beg = rs[node], end = rs[node + 1];
    float d = dinv[node];
    float w0 = d * d;
    ushort4 u = ((const ushort4*)(m + (size_t)node * HDIM))[lane];
    float ax = bf2f(u.x) * w0, ay = bf2f(u.y) * w0, az = bf2f(u.z) * w0, aw = bf2f(u.w) * w0;

    for (int base = beg; base < end; base += 64) {
        int2 ed = (base + lane < end) ? edata[base + lane] : make_int2(0, 0);
        int take = end - base;
        if (take > 64) take = 64;
        for (int e = 0; e < take; e += 4) {
            int s0 = __shfl(ed.x, e + 0);
            int s1 = __shfl(ed.x, e + 1);
            int s2 = __shfl(ed.x, e + 2);
            int s3 = __shfl(ed.x, e + 3);
            float wq0 = __int_as_float(__shfl(ed.y, e + 0));
            float wq1 = __int_as_float(__shfl(ed.y, e + 1));
            float wq2 = __int_as_float(__shfl(ed.y, e + 2));
            float wq3 = __int_as_float(__shfl(ed.y, e + 3));
            ushort4 v0 = ((const ushort4*)(m + (size_t)s0 * HDIM))[lane];
            ushort4 v1 = ((const ushort4*)(m + (size_t)s1 * HDIM))[lane];
            ushort4 v2 = ((const ushort4*)(m + (size_t)s2 * HDIM))[lane];
            ushort4 v3 = ((const ushort4*)(m + (size_t)s3 * HDIM))[lane];
            ax += bf2f(v0.x) * wq0; ay += bf2f(v0.y) * wq0;
            az += bf2f(v0.z) * wq0; aw += bf2f(v0.w) * wq0;
            ax += bf2f(v1.x) * wq1; ay += bf2f(v1.y) * wq1;
            az += bf2f(v1.z) * wq1; aw += bf2f(v1.w) * wq1;
            ax += bf2f(v2.x) * wq2; ay += bf2f(v2.y) * wq2;
            az += bf2f(v2.z) * wq2; aw += bf2f(v2.w) * wq2;
            ax += bf2f(v3.x) * wq3; ay += bf2f(v3.y) * wq3;
            az += bf2f(v3.z) * wq3; aw += bf2f(v3.w) * wq3;
        }
    }

    float4 b = ((const float4*)bias)[lane];
    ax = fmaxf(ax + b.x, 0.0f);
    ay = fmaxf(ay + b.y, 0.0f);
    az = fmaxf(az + b.z, 0.0f);
    aw = fmaxf(aw + b.w, 0.0f);
    if (OUTF32) {
        float4 o = {ax, ay, az, aw};
        ((float4*)out)[(size_t)node * 64 + lane] = o;
    } else {
        ushort4 o;
        o.x = f2bf(ax); o.y = f2bf(ay); o.z = f2bf(az); o.w = f2bf(aw);
        ((ushort4*)out)[(size_t)node * 64 + lane] = o;
    }
}

extern "C" void kernel_launch(void* const* d_in, const int* in_sizes, int n_in,
                              void* d_out, int out_size, void* d_ws, size_t ws_size,
                              hipStream_t stream) {
    const float* x  = (const float*)d_in[0];
    const int* ei   = (const int*)d_in[1];
    const float* w1 = (const float*)d_in[2];
    const float* b1 = (const float*)d_in[3];
    const float* w2 = (const float*)d_in[4];
    const float* b2 = (const float*)d_in[5];
    const float* gw = (const float*)d_in[6];
    const float* gb = (const float*)d_in[7];

    const int N = NNODES, E = NEDGES;
    const int* src = ei;
    const int* dst = ei + E;

    // Workspace layout (~158 MB)
    char* p = (char*)d_ws;
    unsigned short* h1   = (unsigned short*)p; p += (size_t)MPAD * HDIM * 2;  // 51.2 MB
    unsigned short* h    = (unsigned short*)p; p += (size_t)MPAD * HDIM * 2;
    unsigned short* m    = (unsigned short*)p; p += (size_t)MPAD * HDIM * 2;
    unsigned short* w1t  = (unsigned short*)p; p += (size_t)FIN * HDIM * 2;
    unsigned short* gwt  = (unsigned short*)p; p += (size_t)NLAYERS * HDIM * HDIM * 2;
    unsigned short* w2c  = (unsigned short*)p; p += (size_t)HDIM * HDIM * 2;   // w2 bf16 row-major
    unsigned short* fBt  = (unsigned short*)p; p += (size_t)HDIM * HDIM * 2;   // folded W2*G0, Bt layout
    float* foldb = (float*)p;          p += (size_t)HDIM * 4;                  // folded bias b2*G0
    unsigned* cnt = (unsigned*)p;      p += (size_t)N * 4;
    float* dinv = (float*)p;           p += (size_t)N * 4;
    int* rs = (int*)p;                 p += (size_t)(N + 1) * 4 + 12;
    unsigned* blocksum = (unsigned*)p; p += 512 * 4;
    int2* edata = (int2*)p;            p += (size_t)E * 8;   // packed (src, weight)

    // xb: x converted to bf16 [MPAD][FIN] — reuses the idle m buffer (25.6 MB < 51.2 MB)
    unsigned short* xb = m;

    const int nb = (N + 255) / 256;             // 391
    const dim3 ggrid(2, MPAD / 128);            // 1564 blocks, 128x128 tiles

    // ---- Weight conversion + x -> bf16 ----
    wprep_k<<<(FIN * 256 + 255) / 256, 256, 0, stream>>>(w1, w1t, FIN, FIN * 256);
    wprep_k<<<(NLAYERS * HDIM * 256 + 255) / 256, 256, 0, stream>>>(gw, gwt, HDIM, NLAYERS * HDIM * 256);
    conv_k<<<(HDIM * HDIM / 4 + 255) / 256, 256, 0, stream>>>(w2, w2c, HDIM * HDIM / 4);
    conv_k<<<(N * FIN / 4 + 255) / 256, 256, 0, stream>>>(x, xb, N * FIN / 4);

    // ---- Fold: fBt[c][k'] = sum_j G0[j][c]*W2[k'][j];  foldb[c] = sum_j b2[j]*G0[j][c]
    foldbias_k<<<1, 256, 0, stream>>>(b2, gw, foldb);
    gemm_lds_k<HDIM, false, false><<<dim3(2, 2), 256, 0, stream>>>(gwt, w2c, nullptr, fBt);

    // ---- CSR build (6 launches) ----
    zero_k<<<nb, 256, 0, stream>>>(cnt, N);
    count_k<<<(E + 255) / 256, 256, 0, stream>>>(dst, cnt, E);
    scan1_k<<<nb, 256, 0, stream>>>(cnt, rs, blocksum, dinv, N);
    scan2_k<<<1, 512, 0, stream>>>(blocksum, nb);
    scan3_k<<<nb + 1, 256, 0, stream>>>(rs, blocksum, N, E);
    fill_k<<<(E + 255) / 256, 256, 0, stream>>>(src, dst, rs, cnt, dinv, edata, E);

    // ---- Encoder GEMM1: h1 = relu(xb @ W1 + b1) ----
    gemm_lds_k<FIN, true, true><<<ggrid, 256, 0, stream>>>(xb, w1t, b1, h1);

    // ---- Layer 0 (folded): m = h1 @ (W2*G0) + b2*G0  (overwrites xb — already consumed)
    gemm_lds_k<HDIM, true, false><<<ggrid, 256, 0, stream>>>(h1, fBt, foldb, m);
    gather_k<false><<<(N + 3) / 4, 256, 0, stream>>>(rs, edata, dinv, m, gb, h, N);

    // ---- Layers 1..2 ----
    for (int l = 1; l < NLAYERS; ++l) {
        const unsigned short* wl = gwt + (size_t)l * HDIM * HDIM;
        const float* bl = gb + (size_t)l * HDIM;
        gemm_lds_k<HDIM, false, false><<<ggrid, 256, 0, stream>>>(h, wl, nullptr, m);
        if (l < NLAYERS - 1)
            gather_k<false><<<(N + 3) / 4, 256, 0, stream>>>(rs, edata, dinv, m, bl, h, N);
        else
            gather_k<true><<<(N + 3) / 4, 256, 0, stream>>>(rs, edata, dinv, m, bl, d_out, N);
    }
}

// Round 3
// 459.809 us; speedup vs baseline: 1.3084x; 1.0085x over previous
//
#include <hip/hip_runtime.h>
#include <hip/hip_bf16.h>

// Problem constants
#define NNODES 100000
#define NEDGES 300000
#define FIN 128
#define HDIM 256
#define NLAYERS 3
#define MPAD 100096  // 782 * 128 — all GEMMs compute exactly MPAD rows, no predicates

typedef float f32x4 __attribute__((ext_vector_type(4)));
typedef short bf16x8 __attribute__((ext_vector_type(8)));

__device__ inline float bf2f(unsigned short u) {
    union { unsigned int i; float f; } v;
    v.i = ((unsigned int)u) << 16;
    return v.f;
}
__device__ inline unsigned short f2bf(float f) {  // RNE
    union { float f; unsigned int i; } v;
    v.f = f;
    return (unsigned short)((v.i + 0x7fffu + ((v.i >> 16) & 1u)) >> 16);
}

// 16-byte async global->LDS (dest = wave-uniform base + lane*16)
__device__ __forceinline__ void gll16(const unsigned short* g, unsigned short* l) {
    __builtin_amdgcn_global_load_lds(
        (const __attribute__((address_space(1))) unsigned int*)g,
        (__attribute__((address_space(3))) unsigned int*)l, 16, 0, 0);
}

// ---------------------------------------------------------------------------
// Counted-vmcnt pipelined MFMA GEMM (T3/T4-style, 2 stages in flight).
// C[M,256] tile: 128 rows x 128 cols per block, 4 waves (wave = 64x64 via
// 4x4 of 16x16x32 MFMA), BK=32, TRIPLE-buffered LDS (48 KiB).
// Per K-step: vmcnt(4) [only stage(t) drained; stage(t+1) stays in flight]
// -> s_barrier -> issue stage(t+2) -> ds_read buf[t%3] -> 16 MFMA.
// Race audit: reads at iter t hit buf[t%3]; writes issued at iter t target
// buf[(t+2)%3]; the next write to buf[t%3] is issued post-barrier(t+1), which
// no wave passes until all iter-t ds_reads retired (lgkmcnt precedes MFMA).
// vmcnt(4) before the barrier publishes each wave's own stage(t).
// Staging: global_load_lds width=16, LINEAR LDS dest; bank conflicts on
// ds_read_b128 avoided by pre-swizzling the global SOURCE address and
// applying the same XOR on the read side (slot ^= (row>>1)&3) — 2-way max.
// A: bf16 [.][K] row-major.  Bt: bf16 [256][K] (pre-transposed).  C: bf16.
// M must be a multiple of 128 (grid.y = M/128); N tile via grid.x in {0,1}.
// ---------------------------------------------------------------------------
template <int K, bool BIAS, bool RELU>
__global__ __launch_bounds__(256) void gemm_lds_k(
    const unsigned short* __restrict__ A, const unsigned short* __restrict__ Bt,
    const float* __restrict__ bias, unsigned short* __restrict__ C) {
    constexpr int BK = 32;        // 64 B per LDS row
    constexpr int NT = K / BK;    // 4 (K=128) or 8 (K=256)
    __shared__ unsigned short sA[3][128 * BK];
    __shared__ unsigned short sB[3][128 * BK];

    const int tid  = threadIdx.x;
    const int lane = tid & 63;
    const int wid  = tid >> 6;
    const int r15  = lane & 15;
    const int kq   = lane >> 4;        // 0..3
    const int wr   = wid >> 1;         // wave row-tile (0/1)
    const int wc   = wid & 1;          // wave col-tile (0/1)
    const int rowblk = blockIdx.y * 128;
    const int colblk = blockIdx.x * 128;

    // Staging geometry: wave w, chunk q covers LDS rows [q*64 + w*16, +16),
    // each row = 64 B; lane L writes row (L>>2), phys slot (L&3).
    // Phys slot p at row r holds logical k-slot p ^ ((r>>1)&3)  (involution).
    const unsigned short* gA[2];
    const unsigned short* gB[2];
    int ldsbase[2];
#pragma unroll
    for (int q = 0; q < 2; ++q) {
        int rr   = q * 64 + wid * 16 + (lane >> 2);
        int slot = (lane & 3) ^ ((rr >> 1) & 3);
        gA[q] = A  + (size_t)(rowblk + rr) * K + slot * 8;
        gB[q] = Bt + (size_t)(colblk + rr) * K + slot * 8;
        ldsbase[q] = (q * 64 + wid * 16) * BK;   // wave-uniform
    }

    // Read-side swizzled fragment offsets (elements)
    const int sread = ((kq ^ ((r15 >> 1) & 3)) * 8);
    int aoff[4], boff[4];
#pragma unroll
    for (int i = 0; i < 4; ++i) {
        aoff[i] = (wr * 64 + i * 16 + r15) * BK + sread;
        boff[i] = (wc * 64 + i * 16 + r15) * BK + sread;
    }

    f32x4 acc[4][4] = {};

    // prologue: stage K-tiles 0 and 1 into bufs 0 and 1 (8 loads in flight)
#pragma unroll
    for (int q = 0; q < 2; ++q) {
        gll16(gA[q], &sA[0][ldsbase[q]]);
        gll16(gB[q], &sB[0][ldsbase[q]]);
    }
#pragma unroll
    for (int q = 0; q < 2; ++q) {
        gll16(gA[q] + BK, &sA[1][ldsbase[q]]);
        gll16(gB[q] + BK, &sB[1][ldsbase[q]]);
    }

#pragma unroll
    for (int t = 0; t < NT; ++t) {
        // counted drain: only stage(t) must have landed; stage(t+1) stays in flight
        if (t + 1 < NT) {
            asm volatile("s_waitcnt vmcnt(4)" ::: "memory");
        } else {
            asm volatile("s_waitcnt vmcnt(0)" ::: "memory");
        }
        __builtin_amdgcn_s_barrier();
        // issue stage(t+2) AFTER the barrier (its buffer's last readers were
        // iter t-1, all retired before any wave passed this barrier)
        if (t + 2 < NT) {
#pragma unroll
            for (int q = 0; q < 2; ++q) {
                gll16(gA[q] + (t + 2) * BK, &sA[(t + 2) % 3][ldsbase[q]]);
                gll16(gB[q] + (t + 2) * BK, &sB[(t + 2) % 3][ldsbase[q]]);
            }
        }
        bf16x8 a[4], b[4];
#pragma unroll
        for (int i = 0; i < 4; ++i) a[i] = *(const bf16x8*)&sA[t % 3][aoff[i]];
#pragma unroll
        for (int j = 0; j < 4; ++j) b[j] = *(const bf16x8*)&sB[t % 3][boff[j]];
#pragma unroll
        for (int i = 0; i < 4; ++i)
#pragma unroll
            for (int j = 0; j < 4; ++j)
                acc[i][j] = __builtin_amdgcn_mfma_f32_16x16x32_bf16(a[i], b[j], acc[i][j], 0, 0, 0);
    }

    // Epilogue: C/D layout col = lane&15, row = (lane>>4)*4 + reg
#pragma unroll
    for (int i = 0; i < 4; ++i) {
#pragma unroll
        for (int reg = 0; reg < 4; ++reg) {
            int row = rowblk + wr * 64 + i * 16 + kq * 4 + reg;
#pragma unroll
            for (int j = 0; j < 4; ++j) {
                int col = colblk + wc * 64 + j * 16 + r15;
                float v = acc[i][j][reg];
                if (BIAS) v += bias[col];
                if (RELU) v = fmaxf(v, 0.0f);
                C[(size_t)row * HDIM + col] = f2bf(v);
            }
        }
    }
}

// ---------------------------------------------------------------------------
// Weight prep: W[nm][K][256] fp32 -> Wt[nm][256][K] bf16 (transpose+convert)
// ---------------------------------------------------------------------------
__global__ void wprep_k(const float* __restrict__ W, unsigned short* __restrict__ Wt,
                        int K, int total) {
    int i = blockIdx.x * blockDim.x + threadIdx.x;
    if (i >= total) return;
    int mat = i / (K * 256);
    int r = i - mat * (K * 256);
    int k = r >> 8, p = r & 255;
    Wt[(size_t)mat * K * 256 + (size_t)p * K + k] = f2bf(W[i]);
}

// Straight fp32 -> bf16 convert (no transpose), vectorized x4
__global__ void conv_k(const float* __restrict__ W, unsigned short* __restrict__ o, int n4) {
    int i = blockIdx.x * blockDim.x + threadIdx.x;
    if (i >= n4) return;
    float4 v = ((const float4*)W)[i];
    ushort4 u;
    u.x = f2bf(v.x); u.y = f2bf(v.y); u.z = f2bf(v.z); u.w = f2bf(v.w);
    ((ushort4*)o)[i] = u;
}

// foldb[c] = sum_j b2[j] * G0[j][c]   (G0 = gcn_w layer 0, row-major fp32)
__global__ void foldbias_k(const float* __restrict__ b2, const float* __restrict__ g0,
                           float* __restrict__ fb) {
    int c = threadIdx.x;  // one block of 256
    float s = 0.0f;
#pragma unroll 8
    for (int j = 0; j < HDIM; ++j) s += b2[j] * g0[(size_t)j * HDIM + c];
    fb[c] = s;
}

// ---------------------------------------------------------------------------
// CSR build utilities
// ---------------------------------------------------------------------------
__global__ void zero_k(unsigned* __restrict__ p, int n) {
    int i = blockIdx.x * blockDim.x + threadIdx.x;
    if (i < n) p[i] = 0u;
}

__global__ void count_k(const int* __restrict__ dst, unsigned* __restrict__ cnt, int E) {
    int e = blockIdx.x * blockDim.x + threadIdx.x;
    if (e < E) atomicAdd(&cnt[dst[e]], 1u);
}

// scan1 also computes dinv and zeroes cnt (cursor reuse) — saves 2 launches
__global__ __launch_bounds__(256) void scan1_k(unsigned* __restrict__ cnt,
                                               int* __restrict__ rs,
                                               unsigned* __restrict__ blocksum,
                                               float* __restrict__ dinv, int N) {
    __shared__ unsigned tmp[256];
    int tid = threadIdx.x;
    int gid = blockIdx.x * 256 + tid;
    unsigned v = (gid < N) ? cnt[gid] : 0u;
    if (gid < N) {
        dinv[gid] = 1.0f / sqrtf((float)(v + 1u));  // +1 = self loop
        cnt[gid] = 0u;                               // reset for cursor use
    }
    tmp[tid] = v;
    __syncthreads();
#pragma unroll
    for (int off = 1; off < 256; off <<= 1) {
        unsigned t = (tid >= off) ? tmp[tid - off] : 0u;
        __syncthreads();
        tmp[tid] += t;
        __syncthreads();
    }
    if (gid < N) rs[gid] = (int)(tmp[tid] - v);
    if (tid == 255) blocksum[blockIdx.x] = tmp[tid];
}

__global__ __launch_bounds__(512) void scan2_k(unsigned* __restrict__ blocksum, int nb) {
    __shared__ unsigned tmp[512];
    int tid = threadIdx.x;
    unsigned v = (tid < nb) ? blocksum[tid] : 0u;
    tmp[tid] = v;
    __syncthreads();
#pragma unroll
    for (int off = 1; off < 512; off <<= 1) {
        unsigned t = (tid >= off) ? tmp[tid - off] : 0u;
        __syncthreads();
        tmp[tid] += t;
        __syncthreads();
    }
    if (tid < nb) blocksum[tid] = tmp[tid] - v;
}

__global__ void scan3_k(int* __restrict__ rs, const unsigned* __restrict__ blocksum, int N, int E) {
    int gid = blockIdx.x * blockDim.x + threadIdx.x;
    if (gid < N) rs[gid] += (int)blocksum[gid >> 8];
    if (gid == 0) rs[N] = E;
}

// fill_k packs (src, weight) into one int2 per edge — single 8B load in gather
__global__ void fill_k(const int* __restrict__ src, const int* __restrict__ dst,
                       const int* __restrict__ rs, unsigned* __restrict__ cursor,
                       const float* __restrict__ dinv,
                       int2* __restrict__ edata, int E) {
    int e = blockIdx.x * blockDim.x + threadIdx.x;
    if (e >= E) return;
    int s = src[e], d = dst[e];
    int pos = rs[d] + (int)atomicAdd(&cursor[d], 1u);
    float w = dinv[s] * dinv[d];
    edata[pos] = make_int2(s, __float_as_int(w));
}

// ---------------------------------------------------------------------------
// CSR gather-aggregate (bf16 m), fused self-loop + bias + ReLU.
// One wave per node; ushort4 (4 cols) per lane.
// Cooperative edge-metadata load + register shuffle broadcast + 4-wide
// unrolled independent row gathers. Masked slots carry (s=0, w=0.0).
// ---------------------------------------------------------------------------
template <bool OUTF32>
__global__ __launch_bounds__(256) void gather_k(const int* __restrict__ rs,
                                                const int2* __restrict__ edata,
                                                const float* __restrict__ dinv,
                                                const unsigned short* __restrict__ m,
                                                const float* __restrict__ bias,
                                                void* __restrict__ out, int N) {
    int node = blockIdx.x * 4 + (threadIdx.x >> 6);
    int lane = threadIdx.x & 63;
    if (node >= N) return;
    int beg = rs[node], end = rs[node + 1];
    float d = dinv[node];
    float w0 = d * d;
    ushort4 u = ((const ushort4*)(m + (size_t)node * HDIM))[lane];
    float ax = bf2f(u.x) * w0, ay = bf2f(u.y) * w0, az = bf2f(u.z) * w0, aw = bf2f(u.w) * w0;

    for (int base = beg; base < end; base += 64) {
        int2 ed = (base + lane < end) ? edata[base + lane] : make_int2(0, 0);
        int take = end - base;
        if (take > 64) take = 64;
        for (int e = 0; e < take; e += 4) {
            int s0 = __shfl(ed.x, e + 0);
            int s1 = __shfl(ed.x, e + 1);
            int s2 = __shfl(ed.x, e + 2);
            int s3 = __shfl(ed.x, e + 3);
            float wq0 = __int_as_float(__shfl(ed.y, e + 0));
            float wq1 = __int_as_float(__shfl(ed.y, e + 1));
            float wq2 = __int_as_float(__shfl(ed.y, e + 2));
            float wq3 = __int_as_float(__shfl(ed.y, e + 3));
            ushort4 v0 = ((const ushort4*)(m + (size_t)s0 * HDIM))[lane];
            ushort4 v1 = ((const ushort4*)(m + (size_t)s1 * HDIM))[lane];
            ushort4 v2 = ((const ushort4*)(m + (size_t)s2 * HDIM))[lane];
            ushort4 v3 = ((const ushort4*)(m + (size_t)s3 * HDIM))[lane];
            ax += bf2f(v0.x) * wq0; ay += bf2f(v0.y) * wq0;
            az += bf2f(v0.z) * wq0; aw += bf2f(v0.w) * wq0;
            ax += bf2f(v1.x) * wq1; ay += bf2f(v1.y) * wq1;
            az += bf2f(v1.z) * wq1; aw += bf2f(v1.w) * wq1;
            ax += bf2f(v2.x) * wq2; ay += bf2f(v2.y) * wq2;
            az += bf2f(v2.z) * wq2; aw += bf2f(v2.w) * wq2;
            ax += bf2f(v3.x) * wq3; ay += bf2f(v3.y) * wq3;
            az += bf2f(v3.z) * wq3; aw += bf2f(v3.w) * wq3;
        }
    }

    float4 b = ((const float4*)bias)[lane];
    ax = fmaxf(ax + b.x, 0.0f);
    ay = fmaxf(ay + b.y, 0.0f);
    az = fmaxf(az + b.z, 0.0f);
    aw = fmaxf(aw + b.w, 0.0f);
    if (OUTF32) {
        float4 o = {ax, ay, az, aw};
        ((float4*)out)[(size_t)node * 64 + lane] = o;
    } else {
        ushort4 o;
        o.x = f2bf(ax); o.y = f2bf(ay); o.z = f2bf(az); o.w = f2bf(aw);
        ((ushort4*)out)[(size_t)node * 64 + lane] = o;
    }
}

extern "C" void kernel_launch(void* const* d_in, const int* in_sizes, int n_in,
                              void* d_out, int out_size, void* d_ws, size_t ws_size,
                              hipStream_t stream) {
    const float* x  = (const float*)d_in[0];
    const int* ei   = (const int*)d_in[1];
    const float* w1 = (const float*)d_in[2];
    const float* b1 = (const float*)d_in[3];
    const float* w2 = (const float*)d_in[4];
    const float* b2 = (const float*)d_in[5];
    const float* gw = (const float*)d_in[6];
    const float* gb = (const float*)d_in[7];

    const int N = NNODES, E = NEDGES;
    const int* src = ei;
    const int* dst = ei + E;

    // Workspace layout (~158 MB)
    char* p = (char*)d_ws;
    unsigned short* h1   = (unsigned short*)p; p += (size_t)MPAD * HDIM * 2;  // 51.2 MB
    unsigned short* h    = (unsigned short*)p; p += (size_t)MPAD * HDIM * 2;
    unsigned short* m    = (unsigned short*)p; p += (size_t)MPAD * HDIM * 2;
    unsigned short* w1t  = (unsigned short*)p; p += (size_t)FIN * HDIM * 2;
    unsigned short* gwt  = (unsigned short*)p; p += (size_t)NLAYERS * HDIM * HDIM * 2;
    unsigned short* w2c  = (unsigned short*)p; p += (size_t)HDIM * HDIM * 2;   // w2 bf16 row-major
    unsigned short* fBt  = (unsigned short*)p; p += (size_t)HDIM * HDIM * 2;   // folded W2*G0, Bt layout
    float* foldb = (float*)p;          p += (size_t)HDIM * 4;                  // folded bias b2*G0
    unsigned* cnt = (unsigned*)p;      p += (size_t)N * 4;
    float* dinv = (float*)p;           p += (size_t)N * 4;
    int* rs = (int*)p;                 p += (size_t)(N + 1) * 4 + 12;
    unsigned* blocksum = (unsigned*)p; p += 512 * 4;
    int2* edata = (int2*)p;            p += (size_t)E * 8;   // packed (src, weight)

    // xb: x converted to bf16 [MPAD][FIN] — reuses the idle m buffer (25.6 MB < 51.2 MB)
    unsigned short* xb = m;

    const int nb = (N + 255) / 256;             // 391
    const dim3 ggrid(2, MPAD / 128);            // 1564 blocks, 128x128 tiles

    // ---- Weight conversion + x -> bf16 ----
    wprep_k<<<(FIN * 256 + 255) / 256, 256, 0, stream>>>(w1, w1t, FIN, FIN * 256);
    wprep_k<<<(NLAYERS * HDIM * 256 + 255) / 256, 256, 0, stream>>>(gw, gwt, HDIM, NLAYERS * HDIM * 256);
    conv_k<<<(HDIM * HDIM / 4 + 255) / 256, 256, 0, stream>>>(w2, w2c, HDIM * HDIM / 4);
    conv_k<<<(N * FIN / 4 + 255) / 256, 256, 0, stream>>>(x, xb, N * FIN / 4);

    // ---- Fold: fBt[c][k'] = sum_j G0[j][c]*W2[k'][j];  foldb[c] = sum_j b2[j]*G0[j][c]
    foldbias_k<<<1, 256, 0, stream>>>(b2, gw, foldb);
    gemm_lds_k<HDIM, false, false><<<dim3(2, 2), 256, 0, stream>>>(gwt, w2c, nullptr, fBt);

    // ---- CSR build (6 launches) ----
    zero_k<<<nb, 256, 0, stream>>>(cnt, N);
    count_k<<<(E + 255) / 256, 256, 0, stream>>>(dst, cnt, E);
    scan1_k<<<nb, 256, 0, stream>>>(cnt, rs, blocksum, dinv, N);
    scan2_k<<<1, 512, 0, stream>>>(blocksum, nb);
    scan3_k<<<nb + 1, 256, 0, stream>>>(rs, blocksum, N, E);
    fill_k<<<(E + 255) / 256, 256, 0, stream>>>(src, dst, rs, cnt, dinv, edata, E);

    // ---- Encoder GEMM1: h1 = relu(xb @ W1 + b1) ----
    gemm_lds_k<FIN, true, true><<<ggrid, 256, 0, stream>>>(xb, w1t, b1, h1);

    // ---- Layer 0 (folded): m = h1 @ (W2*G0) + b2*G0  (overwrites xb — already consumed)
    gemm_lds_k<HDIM, true, false><<<ggrid, 256, 0, stream>>>(h1, fBt, foldb, m);
    gather_k<false><<<(N + 3) / 4, 256, 0, stream>>>(rs, edata, dinv, m, gb, h, N);

    // ---- Layers 1..2 ----
    for (int l = 1; l < NLAYERS; ++l) {
        const unsigned short* wl = gwt + (size_t)l * HDIM * HDIM;
        const float* bl = gb + (size_t)l * HDIM;
        gemm_lds_k<HDIM, false, false><<<ggrid, 256, 0, stream>>>(h, wl, nullptr, m);
        if (l < NLAYERS - 1)
            gather_k<false><<<(N + 3) / 4, 256, 0, stream>>>(rs, edata, dinv, m, bl, h, N);
        else
            gather_k<true><<<(N + 3) / 4, 256, 0, stream>>>(rs, edata, dinv, m, bl, d_out, N);
    }
}